// Round 1
// baseline (682.297 us; speedup 1.0000x reference)
//
#include <hip/hip_runtime.h>
#include <math.h>

constexpr int B_ = 4;
constexpr int N_ = 16384;
constexpr int DIN = 256;
constexpr int H_ = 8;
constexpr int DOUT = 512;
constexpr int R_ = B_ * N_;   // 65536

// ---------------- workspace layout (float offsets) ----------------
constexpr size_t o_Gq    = 0;         // 256x256 global query gram
constexpr size_t o_Gs    = 65536;     // 4 x 256x256 per-batch source grams
constexpr size_t o_uq    = 327680;    // 256 colsum(query)
constexpr size_t o_us    = 327936;    // 4x256 colsum(source_b)
constexpr size_t o_nrm   = 328960;    // [0]=nq2 [1]=nk2
constexpr size_t ZERO_FLOATS = 329024; // everything above is atomically accumulated -> zero each call
constexpr size_t o_Pv    = 329024;    // 4 x (256x512): G_b @ Wv^T
constexpr size_t o_Pk    = 853312;    // 4 x (256x512): G_b @ Wk^T
constexpr size_t o_Pq    = 1377600;   // 256x512: Gq @ Wq^T
constexpr size_t o_wku   = 1508672;   // 4x512: Wk[c]·u_b
constexpr size_t o_wvu   = 1510720;   // 4x512: Wv[c]·u_b
constexpr size_t o_kssum = 1512768;   // 4x512
constexpr size_t o_vssum = 1514816;   // 4x512
constexpr size_t o_kv    = 1516864;   // 4x8x64x64 raw K^T V
constexpr size_t o_W1t   = 1647936;   // 4 x (256 i x 512 c), s folded in
constexpr size_t o_w2    = 2172224;   // 4x8x256, s folded in
constexpr size_t o_C1    = 2180416;   // 4x512  (s*bq·kv + vs_sum)
constexpr size_t o_C2    = 2182464;   // 4x8    (s*bq·ks_sum + N)
constexpr size_t WS_FLOATS = 2182528; // ~8.73 MB

static __device__ __forceinline__ float dot4(float4 a, float4 b) {
  return a.x * b.x + a.y * b.y + a.z * b.z + a.w * b.w;
}

// ---------------- 1) Grams: G = A^T A (256x256) + colsum ----------------
// grid (16 tiles, 16 kchunks, 8): z<4 -> source batch z ; z>=4 -> query quarter (shared Gq)
__global__ __launch_bounds__(256) void gram_k(const float* __restrict__ Xq,
                                              const float* __restrict__ Xsrc,
                                              float* __restrict__ ws) {
  const int z = blockIdx.z;
  const float* A;
  float* G;
  float* u;
  if (z < 4) {
    A = Xsrc + (size_t)z * N_ * DIN;
    G = ws + o_Gs + (size_t)z * 65536;
    u = ws + o_us + z * 256;
  } else {
    A = Xq + (size_t)(z - 4) * N_ * DIN;
    G = ws + o_Gq;
    u = ws + o_uq;
  }
  const int tile = blockIdx.x;
  const int i0 = (tile >> 2) * 64, j0 = (tile & 3) * 64;
  const bool diag = (i0 == j0);
  __shared__ float Ai[16][64];
  __shared__ float Aj[16][64];
  const int tid = threadIdx.x;
  const int lrow = tid >> 4, lc4 = (tid & 15) * 4;
  const int ty = tid >> 4, tx = tid & 15;
  float acc[4][4] = {};
  float usum = 0.f;
  const int r0 = blockIdx.y * 1024;
  for (int r = r0; r < r0 + 1024; r += 16) {
    const float4 va = *(const float4*)&A[(size_t)(r + lrow) * DIN + i0 + lc4];
    const float4 vb = *(const float4*)&A[(size_t)(r + lrow) * DIN + j0 + lc4];
    __syncthreads();
    *(float4*)&Ai[lrow][lc4] = va;
    *(float4*)&Aj[lrow][lc4] = vb;
    __syncthreads();
#pragma unroll
    for (int k = 0; k < 16; ++k) {
      const float4 a = *(const float4*)&Ai[k][ty * 4];
      const float4 bb = *(const float4*)&Aj[k][tx * 4];
      const float av[4] = {a.x, a.y, a.z, a.w};
      const float bv_[4] = {bb.x, bb.y, bb.z, bb.w};
#pragma unroll
      for (int i = 0; i < 4; ++i)
#pragma unroll
        for (int j = 0; j < 4; ++j) acc[i][j] += av[i] * bv_[j];
    }
    if (diag) {
      const int col = tid & 63, part = tid >> 6;
#pragma unroll
      for (int k = 0; k < 4; ++k) usum += Ai[part * 4 + k][col];
    }
  }
#pragma unroll
  for (int i = 0; i < 4; ++i)
#pragma unroll
    for (int j = 0; j < 4; ++j)
      atomicAdd(&G[(size_t)(i0 + ty * 4 + i) * DIN + j0 + tx * 4 + j], acc[i][j]);
  if (diag) {
    __syncthreads();
    ((float*)Ai)[tid] = usum;
    __syncthreads();
    if (tid < 64) {
      const float s = ((float*)Ai)[tid] + ((float*)Ai)[64 + tid] +
                      ((float*)Ai)[128 + tid] + ((float*)Ai)[192 + tid];
      atomicAdd(&u[i0 + tid], s);
    }
  }
}

// ---------------- 2) P = G @ W^T  (256x512, K=256) ----------------
// grid (8 ctiles, 4 itiles, 9 jobs)
__global__ __launch_bounds__(256) void p_k(const float* __restrict__ Wq,
                                           const float* __restrict__ Wk,
                                           const float* __restrict__ Wv,
                                           float* __restrict__ ws) {
  const int job = blockIdx.z;
  const float* G;
  const float* W;
  float* P;
  if (job < 4) {
    G = ws + o_Gs + (size_t)job * 65536; W = Wv; P = ws + o_Pv + (size_t)job * 131072;
  } else if (job < 8) {
    G = ws + o_Gs + (size_t)(job - 4) * 65536; W = Wk; P = ws + o_Pk + (size_t)(job - 4) * 131072;
  } else {
    G = ws + o_Gq; W = Wq; P = ws + o_Pq;
  }
  const int c0 = blockIdx.x * 64, i0 = blockIdx.y * 64;
  __shared__ float Gt[64][68];
  __shared__ float Wt[64][68];
  const int tid = threadIdx.x;
  const int ty = tid >> 4, tx = tid & 15;
  float acc[4][4] = {};
  for (int k0 = 0; k0 < 256; k0 += 64) {
    __syncthreads();
#pragma unroll
    for (int p = 0; p < 4; ++p) {
      const int idx = tid + p * 256;
      const int row = idx >> 4, jq = (idx & 15) * 4;
      const float4 g = *(const float4*)&G[(size_t)(i0 + row) * DIN + k0 + jq];
      Gt[jq + 0][row] = g.x; Gt[jq + 1][row] = g.y; Gt[jq + 2][row] = g.z; Gt[jq + 3][row] = g.w;
      const float4 w = *(const float4*)&W[(size_t)(c0 + row) * DIN + k0 + jq];
      Wt[jq + 0][row] = w.x; Wt[jq + 1][row] = w.y; Wt[jq + 2][row] = w.z; Wt[jq + 3][row] = w.w;
    }
    __syncthreads();
#pragma unroll
    for (int k = 0; k < 64; ++k) {
      const float4 a = *(const float4*)&Gt[k][ty * 4];
      const float4 bb = *(const float4*)&Wt[k][tx * 4];
      const float av[4] = {a.x, a.y, a.z, a.w};
      const float bv_[4] = {bb.x, bb.y, bb.z, bb.w};
#pragma unroll
      for (int ii = 0; ii < 4; ++ii)
#pragma unroll
        for (int jj = 0; jj < 4; ++jj) acc[ii][jj] += av[ii] * bv_[jj];
    }
  }
#pragma unroll
  for (int ii = 0; ii < 4; ++ii)
    *(float4*)&P[(size_t)(i0 + ty * 4 + ii) * DOUT + c0 + tx * 4] =
        make_float4(acc[ii][0], acc[ii][1], acc[ii][2], acc[ii][3]);
}

// ---------------- 3) small bilinears: wku/wvu, ks_sum/vs_sum, nq2/nk2 ----------------
// grid (8 cchunks, 5 jobs): job<4 -> batch; job 4 -> query norm
__global__ __launch_bounds__(256) void s1_k(const float* __restrict__ Wq,
                                            const float* __restrict__ Wk,
                                            const float* __restrict__ Wv,
                                            const float* __restrict__ bq,
                                            const float* __restrict__ bk,
                                            const float* __restrict__ bv,
                                            float* __restrict__ ws) {
  const int tid = threadIdx.x;
  const int c = blockIdx.x * 64 + (tid >> 2);
  const int part = tid & 3;
  const int i0 = part * 64;
  const int job = blockIdx.y;
  __shared__ float red[256];
  float np = 0.f;
  if (job < 4) {
    const int b = job;
    const float* ub = ws + o_us + b * 256;
    const float* wkr = Wk + (size_t)c * 256;
    const float* wvr = Wv + (size_t)c * 256;
    const float* pk = ws + o_Pk + (size_t)b * 131072 + c;
    float dku = 0.f, dvu = 0.f, dpk = 0.f;
#pragma unroll 4
    for (int t = 0; t < 16; ++t) {
      const float4 u4 = *(const float4*)&ub[i0 + t * 4];
      dku += dot4(*(const float4*)&wkr[i0 + t * 4], u4);
      dvu += dot4(*(const float4*)&wvr[i0 + t * 4], u4);
    }
    for (int i = i0; i < i0 + 64; ++i) dpk += wkr[i] * pk[(size_t)i * 512];
    dku += __shfl_down(dku, 2); dku += __shfl_down(dku, 1);
    dvu += __shfl_down(dvu, 2); dvu += __shfl_down(dvu, 1);
    dpk += __shfl_down(dpk, 2); dpk += __shfl_down(dpk, 1);
    if (part == 0) {
      ws[o_wku + b * 512 + c] = dku;
      ws[o_wvu + b * 512 + c] = dvu;
      ws[o_kssum + b * 512 + c] = dku + (float)N_ * bk[c];
      ws[o_vssum + b * 512 + c] = dvu + (float)N_ * bv[c];
      np = dpk + 2.f * bk[c] * dku + (float)N_ * bk[c] * bk[c];
    }
    red[tid] = np;
    __syncthreads();
    for (int s = 128; s > 0; s >>= 1) {
      if (tid < s) red[tid] += red[tid + s];
      __syncthreads();
    }
    if (tid == 0) atomicAdd(&ws[o_nrm + 1], red[0]);
  } else {
    const float* uq = ws + o_uq;
    const float* wqr = Wq + (size_t)c * 256;
    const float* pq = ws + o_Pq + c;
    float dqu = 0.f, dpq = 0.f;
#pragma unroll 4
    for (int t = 0; t < 16; ++t)
      dqu += dot4(*(const float4*)&wqr[i0 + t * 4], *(const float4*)&uq[i0 + t * 4]);
    for (int i = i0; i < i0 + 64; ++i) dpq += wqr[i] * pq[(size_t)i * 512];
    dqu += __shfl_down(dqu, 2); dqu += __shfl_down(dqu, 1);
    dpq += __shfl_down(dpq, 2); dpq += __shfl_down(dpq, 1);
    if (part == 0) np = dpq + 2.f * bq[c] * dqu + (float)R_ * bq[c] * bq[c];
    red[tid] = np;
    __syncthreads();
    for (int s = 128; s > 0; s >>= 1) {
      if (tid < s) red[tid] += red[tid + s];
      __syncthreads();
    }
    if (tid == 0) atomicAdd(&ws[o_nrm], red[0]);
  }
}

// ---------------- 4) kv[b,h] = Wk_h (G_b Wv_h^T) + rank-1 terms ----------------
// grid (32 bh, 4 quarters)
__global__ __launch_bounds__(256) void kv_k(const float* __restrict__ Wk,
                                            const float* __restrict__ bk,
                                            const float* __restrict__ bv,
                                            float* __restrict__ ws) {
  const int bh = blockIdx.x, b = bh >> 3, h = bh & 7;
  const int o0 = blockIdx.y * 1024 + threadIdx.x * 4;
  const int m = o0 >> 6, d0 = o0 & 63;
  const float* pv = ws + o_Pv + (size_t)b * 131072 + h * 64 + d0;
  const float* wk = Wk + (size_t)(h * 64 + m) * 256;
  float acc[4] = {0.f, 0.f, 0.f, 0.f};
  for (int i = 0; i < 256; ++i) {
    const float w = wk[i];
    const float4 p = *(const float4*)&pv[(size_t)i * 512];
    acc[0] += w * p.x; acc[1] += w * p.y; acc[2] += w * p.z; acc[3] += w * p.w;
  }
  const float wkum = ws[o_wku + b * 512 + h * 64 + m];
  const float bkm = bk[h * 64 + m];
  const float* wvup = ws + o_wvu + b * 512 + h * 64 + d0;
  const float* bvp = bv + h * 64 + d0;
  float rr[4];
#pragma unroll
  for (int e = 0; e < 4; ++e)
    rr[e] = acc[e] + wkum * bvp[e] + bkm * wvup[e] + (float)N_ * bkm * bvp[e];
  *(float4*)&ws[o_kv + (size_t)bh * 4096 + (size_t)m * 64 + d0] =
      make_float4(rr[0], rr[1], rr[2], rr[3]);
}

// ---------------- 5) W1t/w2/C1/C2 (fold s = 1/(nq*nk)) ----------------
// grid (4 b, 256 i), 512 threads
__global__ __launch_bounds__(512) void w1_k(const float* __restrict__ Wq,
                                            const float* __restrict__ bq,
                                            float* __restrict__ ws) {
  const int b = blockIdx.x, i = blockIdx.y;
  const int c = threadIdx.x, h = c >> 6, d = c & 63;
  const float s = 1.f / (sqrtf(ws[o_nrm]) * sqrtf(ws[o_nrm + 1]));
  const float* kvp = ws + o_kv + (size_t)(b * 8 + h) * 4096 + d;
  float a = 0.f;
#pragma unroll 4
  for (int m = 0; m < 64; ++m) a += Wq[(size_t)(h * 64 + m) * 256 + i] * kvp[(size_t)m * 64];
  ws[o_W1t + (size_t)b * 131072 + (size_t)i * 512 + c] = s * a;
  if (c < 8) {
    float w = 0.f;
    const float* ksp = ws + o_kssum + b * 512 + c * 64;
#pragma unroll 4
    for (int m = 0; m < 64; ++m) w += Wq[(size_t)(c * 64 + m) * 256 + i] * ksp[m];
    ws[o_w2 + (size_t)(b * 8 + c) * 256 + i] = s * w;
  }
  if (i == 0) {
    float c1 = 0.f;
    for (int m = 0; m < 64; ++m) c1 += bq[h * 64 + m] * kvp[(size_t)m * 64];
    ws[o_C1 + b * 512 + c] = s * c1 + ws[o_vssum + b * 512 + c];
    if (c < 8) {
      float c2 = 0.f;
      const float* ksp = ws + o_kssum + b * 512 + c * 64;
      for (int m = 0; m < 64; ++m) c2 += bq[c * 64 + m] * ksp[m];
      ws[o_C2 + b * 8 + c] = s * c2 + (float)N_;
    }
  }
}

// ---------------- 6) output GEMM + fused den + mean over heads ----------------
// grid (R/32), 256 threads: 32 rows x 512 cols, K=256
__global__ __launch_bounds__(256) void out_k(const float* __restrict__ X,
                                             const float* __restrict__ ws,
                                             float* __restrict__ out) {
  __shared__ float Xs[16][36];     // k-major, padded (2-way max)
  __shared__ float W1s[16][512];
  __shared__ float w2s[8][260];
  __shared__ float denL[32][9];
  const int tid = threadIdx.x;
  const int r0 = blockIdx.x * 32;
  const int b = r0 / N_;
  const float* W1 = ws + o_W1t + (size_t)b * 131072;
  {
    const float* w2p = ws + o_w2 + b * 2048;
#pragma unroll
    for (int p = 0; p < 2; ++p) {
      const int idx4 = tid + p * 256;
      const int h = idx4 >> 6, i4 = (idx4 & 63) * 4;
      *(float4*)&w2s[h][i4] = *(const float4*)&w2p[h * 256 + i4];
    }
  }
  const int tg = tid >> 5, cg = tid & 31;
  const int drow = tid >> 3, dh = tid & 7;
  float acc[4][4][4] = {};
  float den = 0.f;
  for (int kc = 0; kc < 16; ++kc) {
    const int k0 = kc * 16;
    const int srow = tid >> 2, skq = tid & 3;
    float4 xv = make_float4(0.f, 0.f, 0.f, 0.f);
    if (tid < 128) xv = *(const float4*)&X[(size_t)(r0 + srow) * DIN + k0 + skq * 4];
    float4 wv[8];
#pragma unroll
    for (int p = 0; p < 8; ++p) {
      const int idx4 = tid + p * 256;
      const int kk = idx4 >> 7, c4 = (idx4 & 127) * 4;
      wv[p] = *(const float4*)&W1[(size_t)(k0 + kk) * DOUT + c4];
    }
    __syncthreads();
    if (tid < 128) {
      Xs[skq * 4 + 0][srow] = xv.x;
      Xs[skq * 4 + 1][srow] = xv.y;
      Xs[skq * 4 + 2][srow] = xv.z;
      Xs[skq * 4 + 3][srow] = xv.w;
    }
#pragma unroll
    for (int p = 0; p < 8; ++p) {
      const int idx4 = tid + p * 256;
      const int kk = idx4 >> 7, c4 = (idx4 & 127) * 4;
      *(float4*)&W1s[kk][c4] = wv[p];
    }
    __syncthreads();
#pragma unroll
    for (int k = 0; k < 16; ++k) {
      const float4 a = *(const float4*)&Xs[k][tg * 4];
      const float av[4] = {a.x, a.y, a.z, a.w};
#pragma unroll
      for (int sg = 0; sg < 4; ++sg) {
        const float4 bb = *(const float4*)&W1s[k][sg * 128 + cg * 4];
        const float bv_[4] = {bb.x, bb.y, bb.z, bb.w};
#pragma unroll
        for (int rr = 0; rr < 4; ++rr)
#pragma unroll
          for (int e = 0; e < 4; ++e) acc[rr][sg][e] += av[rr] * bv_[e];
      }
      den += Xs[k][drow] * w2s[dh][k0 + k];
    }
  }
  __syncthreads();
  denL[drow][dh] = den + ws[o_C2 + b * 8 + dh];
  __syncthreads();
  const float* C1p = ws + o_C1 + b * 512;
#pragma unroll
  for (int rr = 0; rr < 4; ++rr) {
    const int row = tg * 4 + rr;
    float o4[4] = {0.f, 0.f, 0.f, 0.f};
#pragma unroll
    for (int sg = 0; sg < 4; ++sg) {
      const int h = sg * 2 + (cg >> 4);
      const float dv = denL[row][h];
      const float4 c1 = *(const float4*)&C1p[sg * 128 + cg * 4];
      const float c1v[4] = {c1.x, c1.y, c1.z, c1.w};
#pragma unroll
      for (int e = 0; e < 4; ++e) o4[e] += (acc[rr][sg][e] + c1v[e]) / dv;
    }
#pragma unroll
    for (int e = 0; e < 4; ++e) o4[e] += __shfl_xor(o4[e], 16);
    if (cg < 16)
      *(float4*)&out[(size_t)(r0 + row) * 64 + cg * 4] =
          make_float4(o4[0] * 0.125f, o4[1] * 0.125f, o4[2] * 0.125f, o4[3] * 0.125f);
  }
}

extern "C" void kernel_launch(void* const* d_in, const int* in_sizes, int n_in,
                              void* d_out, int out_size, void* d_ws, size_t ws_size,
                              hipStream_t stream) {
  const float* Xq = (const float*)d_in[0];
  const float* Xsrc = (const float*)d_in[1];
  const float* Wq = (const float*)d_in[2];
  const float* bq = (const float*)d_in[3];
  const float* Wk = (const float*)d_in[4];
  const float* bk = (const float*)d_in[5];
  const float* Wv = (const float*)d_in[6];
  const float* bv = (const float*)d_in[7];
  float* out = (float*)d_out;
  float* ws = (float*)d_ws;
  if (ws_size < WS_FLOATS * sizeof(float)) return;  // need ~8.8 MB scratch

  hipMemsetAsync(ws, 0, ZERO_FLOATS * sizeof(float), stream);
  gram_k<<<dim3(16, 16, 8), 256, 0, stream>>>(Xq, Xsrc, ws);
  p_k<<<dim3(8, 4, 9), 256, 0, stream>>>(Wq, Wk, Wv, ws);
  s1_k<<<dim3(8, 5), 256, 0, stream>>>(Wq, Wk, Wv, bq, bk, bv, ws);
  kv_k<<<dim3(32, 4), 256, 0, stream>>>(Wk, bk, bv, ws);
  w1_k<<<dim3(4, 256), 512, 0, stream>>>(Wq, bq, ws);
  out_k<<<dim3(2048), 256, 0, stream>>>(Xq, ws, out);
}

// Round 2
// 208.754 us; speedup vs baseline: 3.2684x; 3.2684x over previous
//
#include <hip/hip_runtime.h>
#include <math.h>

constexpr int B_ = 4;
constexpr int N_ = 16384;
constexpr int DIN = 256;
constexpr int H_ = 8;
constexpr int DOUT = 512;
constexpr int R_ = B_ * N_;   // 65536

typedef __attribute__((ext_vector_type(4))) float f32x4;
typedef __attribute__((ext_vector_type(8))) short short8;

// ---------------- workspace layout (float offsets) ----------------
constexpr size_t o_Gq    = 0;         // 256x256 global query gram
constexpr size_t o_Gs    = 65536;     // 4 x 256x256 per-batch source grams
constexpr size_t o_uq    = 327680;    // 256 colsum(query)
constexpr size_t o_us    = 327936;    // 4x256 colsum(source_b)
constexpr size_t o_nrm   = 328960;    // [0]=nq2 [1]=nk2
constexpr size_t ZERO_FLOATS = 329024; // atomically accumulated region -> zero each call
constexpr size_t o_Pv    = 329024;    // 4 x (256x512): G_b @ Wv^T
constexpr size_t o_Pk    = 853312;    // 4 x (256x512): G_b @ Wk^T
constexpr size_t o_Pq    = 1377600;   // 256x512: Gq @ Wq^T
constexpr size_t o_wku   = 1508672;   // 4x512: Wk[c]·u_b
constexpr size_t o_wvu   = 1510720;   // 4x512: Wv[c]·u_b
constexpr size_t o_kssum = 1512768;   // 4x512
constexpr size_t o_vssum = 1514816;   // 4x512
constexpr size_t o_kv    = 1516864;   // 4x8x64x64 raw K^T V
constexpr size_t o_W1bt  = 1647936;   // bf16: 4 x [512 c][256 k]  (s folded in)
constexpr size_t o_w2bt  = 1910080;   // bf16: 4 x [16 c][256 k]   (rows 8..15 zero)
constexpr size_t o_C1    = 1918272;   // 4x512  (s*bq·kv + vs_sum), fp32
constexpr size_t o_C2    = 1920320;   // 4x8    (s*bq·ks_sum + N), fp32
constexpr size_t WS_FLOATS = 1920352; // ~7.7 MB

static __device__ __forceinline__ float dot4(float4 a, float4 b) {
  return a.x * b.x + a.y * b.y + a.z * b.z + a.w * b.w;
}

// fp32 -> bf16 bits, round-to-nearest-even
static __device__ __forceinline__ unsigned short f2b(float f) {
  unsigned int u = __float_as_uint(f);
  u = (u + 0x7FFFu + ((u >> 16) & 1u)) >> 16;
  return (unsigned short)u;
}

// ---------------- 1) Grams: G = A^T A (256x256) + colsum, bf16 MFMA ----------------
// grid (32 chunks of 512 rows, 8 z): z<4 -> source batch z ; z>=4 -> query quarter (shared Gq)
__global__ __launch_bounds__(512) void gram_k(const float* __restrict__ Xq,
                                              const float* __restrict__ Xsrc,
                                              float* __restrict__ ws) {
  const int z = blockIdx.y;
  const float* A;
  float* G;
  float* u;
  if (z < 4) {
    A = Xsrc + (size_t)z * N_ * DIN;
    G = ws + o_Gs + (size_t)z * 65536;
    u = ws + o_us + z * 256;
  } else {
    A = Xq + (size_t)(z - 4) * N_ * DIN;
    G = ws + o_Gq;
    u = ws + o_uq;
  }
  const int row0 = blockIdx.x * 512;
  const int tid = threadIdx.x;
  const int lane = tid & 63, wv = tid >> 6;
  const int i0w = (wv >> 1) * 64;       // wave tile: 64 (i) x 128 (j)
  const int j0w = (wv & 1) * 128;
  const int lc = lane & 15;
  const int klb = (lane >> 4) * 16;     // byte offset of this lane's k-octet

  // LDS: A-chunk transposed [256 cols][64 rows] bf16, XOR-swizzled (128B rows)
  __shared__ __align__(16) unsigned short As[256 * 64];
  char* Ab = (char*)As;

  const int c = tid & 255;              // staging: this thread's column
  const int half = tid >> 8;            // rows half*32 .. +32
  float usum = 0.f;

  f32x4 acc[4][8] = {};

  for (int kb = 0; kb < 512; kb += 64) {
    __syncthreads();
    // stage rows [row0+kb, +64): thread reads 32 fp32 down column c, packs bf16
    {
      const float* src = A + (size_t)(row0 + kb + half * 32) * DIN + c;
      const int swz = (c & 7) << 4;
#pragma unroll
      for (int g = 0; g < 4; ++g) {
        float v[8];
#pragma unroll
        for (int e = 0; e < 8; ++e) v[e] = src[(size_t)(g * 8 + e) * DIN];
#pragma unroll
        for (int e = 0; e < 8; ++e) usum += v[e];
        short8 p;
#pragma unroll
        for (int e = 0; e < 8; ++e) p[e] = (short)f2b(v[e]);
        *(short8*)(Ab + ((c * 128 + (half * 32 + g * 8) * 2) ^ swz)) = p;
      }
    }
    __syncthreads();
#pragma unroll
    for (int ks = 0; ks < 2; ++ks) {
      const int kbyte = ks * 64;
      short8 a[4], b[8];
#pragma unroll
      for (int fi = 0; fi < 4; ++fi) {
        const int cc = i0w + fi * 16 + lc;
        a[fi] = *(const short8*)(Ab + ((cc * 128 + kbyte + klb) ^ ((cc & 7) << 4)));
      }
#pragma unroll
      for (int fj = 0; fj < 8; ++fj) {
        const int cc = j0w + fj * 16 + lc;
        b[fj] = *(const short8*)(Ab + ((cc * 128 + kbyte + klb) ^ ((cc & 7) << 4)));
      }
#pragma unroll
      for (int fi = 0; fi < 4; ++fi)
#pragma unroll
        for (int fj = 0; fj < 8; ++fj)
          acc[fi][fj] = __builtin_amdgcn_mfma_f32_16x16x32_bf16(a[fi], b[fj], acc[fi][fj], 0, 0, 0);
    }
  }
  // accumulate into G (fp32 atomics); G symmetric so orientation-safe
#pragma unroll
  for (int fi = 0; fi < 4; ++fi) {
    const int ib = i0w + fi * 16 + (lane >> 4) * 4;
#pragma unroll
    for (int fj = 0; fj < 8; ++fj) {
      const int jb = j0w + fj * 16 + lc;
#pragma unroll
      for (int r = 0; r < 4; ++r)
        atomicAdd(&G[(size_t)(ib + r) * DIN + jb], acc[fi][fj][r]);
    }
  }
  // colsum reduce (fp32, exact)
  __syncthreads();
  float* red = (float*)As;
  red[tid] = usum;
  __syncthreads();
  if (tid < 256) atomicAdd(&u[tid], red[tid] + red[tid + 256]);
}

// ---------------- 2) P = G @ W^T  (256x512, K=256) ----------------
// grid (8 ctiles, 4 itiles, 9 jobs)
__global__ __launch_bounds__(256) void p_k(const float* __restrict__ Wq,
                                           const float* __restrict__ Wk,
                                           const float* __restrict__ Wv,
                                           float* __restrict__ ws) {
  const int job = blockIdx.z;
  const float* G;
  const float* W;
  float* P;
  if (job < 4) {
    G = ws + o_Gs + (size_t)job * 65536; W = Wv; P = ws + o_Pv + (size_t)job * 131072;
  } else if (job < 8) {
    G = ws + o_Gs + (size_t)(job - 4) * 65536; W = Wk; P = ws + o_Pk + (size_t)(job - 4) * 131072;
  } else {
    G = ws + o_Gq; W = Wq; P = ws + o_Pq;
  }
  const int c0 = blockIdx.x * 64, i0 = blockIdx.y * 64;
  __shared__ float Gt[64][68];
  __shared__ float Wt[64][68];
  const int tid = threadIdx.x;
  const int ty = tid >> 4, tx = tid & 15;
  float acc[4][4] = {};
  for (int k0 = 0; k0 < 256; k0 += 64) {
    __syncthreads();
#pragma unroll
    for (int p = 0; p < 4; ++p) {
      const int idx = tid + p * 256;
      const int row = idx >> 4, jq = (idx & 15) * 4;
      const float4 g = *(const float4*)&G[(size_t)(i0 + row) * DIN + k0 + jq];
      Gt[jq + 0][row] = g.x; Gt[jq + 1][row] = g.y; Gt[jq + 2][row] = g.z; Gt[jq + 3][row] = g.w;
      const float4 w = *(const float4*)&W[(size_t)(c0 + row) * DIN + k0 + jq];
      Wt[jq + 0][row] = w.x; Wt[jq + 1][row] = w.y; Wt[jq + 2][row] = w.z; Wt[jq + 3][row] = w.w;
    }
    __syncthreads();
#pragma unroll
    for (int k = 0; k < 64; ++k) {
      const float4 a = *(const float4*)&Gt[k][ty * 4];
      const float4 bb = *(const float4*)&Wt[k][tx * 4];
      const float av[4] = {a.x, a.y, a.z, a.w};
      const float bv_[4] = {bb.x, bb.y, bb.z, bb.w};
#pragma unroll
      for (int ii = 0; ii < 4; ++ii)
#pragma unroll
        for (int jj = 0; jj < 4; ++jj) acc[ii][jj] += av[ii] * bv_[jj];
    }
  }
#pragma unroll
  for (int ii = 0; ii < 4; ++ii)
    *(float4*)&P[(size_t)(i0 + ty * 4 + ii) * DOUT + c0 + tx * 4] =
        make_float4(acc[ii][0], acc[ii][1], acc[ii][2], acc[ii][3]);
}

// ---------------- 3) small bilinears: wku/wvu, ks_sum/vs_sum, nq2/nk2 ----------------
__global__ __launch_bounds__(256) void s1_k(const float* __restrict__ Wq,
                                            const float* __restrict__ Wk,
                                            const float* __restrict__ Wv,
                                            const float* __restrict__ bq,
                                            const float* __restrict__ bk,
                                            const float* __restrict__ bv,
                                            float* __restrict__ ws) {
  const int tid = threadIdx.x;
  const int c = blockIdx.x * 64 + (tid >> 2);
  const int part = tid & 3;
  const int i0 = part * 64;
  const int job = blockIdx.y;
  __shared__ float red[256];
  float np = 0.f;
  if (job < 4) {
    const int b = job;
    const float* ub = ws + o_us + b * 256;
    const float* wkr = Wk + (size_t)c * 256;
    const float* wvr = Wv + (size_t)c * 256;
    const float* pk = ws + o_Pk + (size_t)b * 131072 + c;
    float dku = 0.f, dvu = 0.f, dpk = 0.f;
#pragma unroll 4
    for (int t = 0; t < 16; ++t) {
      const float4 u4 = *(const float4*)&ub[i0 + t * 4];
      dku += dot4(*(const float4*)&wkr[i0 + t * 4], u4);
      dvu += dot4(*(const float4*)&wvr[i0 + t * 4], u4);
    }
    for (int i = i0; i < i0 + 64; ++i) dpk += wkr[i] * pk[(size_t)i * 512];
    dku += __shfl_down(dku, 2); dku += __shfl_down(dku, 1);
    dvu += __shfl_down(dvu, 2); dvu += __shfl_down(dvu, 1);
    dpk += __shfl_down(dpk, 2); dpk += __shfl_down(dpk, 1);
    if (part == 0) {
      ws[o_wku + b * 512 + c] = dku;
      ws[o_wvu + b * 512 + c] = dvu;
      ws[o_kssum + b * 512 + c] = dku + (float)N_ * bk[c];
      ws[o_vssum + b * 512 + c] = dvu + (float)N_ * bv[c];
      np = dpk + 2.f * bk[c] * dku + (float)N_ * bk[c] * bk[c];
    }
    red[tid] = np;
    __syncthreads();
    for (int s = 128; s > 0; s >>= 1) {
      if (tid < s) red[tid] += red[tid + s];
      __syncthreads();
    }
    if (tid == 0) atomicAdd(&ws[o_nrm + 1], red[0]);
  } else {
    const float* uq = ws + o_uq;
    const float* wqr = Wq + (size_t)c * 256;
    const float* pq = ws + o_Pq + c;
    float dqu = 0.f, dpq = 0.f;
#pragma unroll 4
    for (int t = 0; t < 16; ++t)
      dqu += dot4(*(const float4*)&wqr[i0 + t * 4], *(const float4*)&uq[i0 + t * 4]);
    for (int i = i0; i < i0 + 64; ++i) dpq += wqr[i] * pq[(size_t)i * 512];
    dqu += __shfl_down(dqu, 2); dqu += __shfl_down(dqu, 1);
    dpq += __shfl_down(dpq, 2); dpq += __shfl_down(dpq, 1);
    if (part == 0) np = dpq + 2.f * bq[c] * dqu + (float)R_ * bq[c] * bq[c];
    red[tid] = np;
    __syncthreads();
    for (int s = 128; s > 0; s >>= 1) {
      if (tid < s) red[tid] += red[tid + s];
      __syncthreads();
    }
    if (tid == 0) atomicAdd(&ws[o_nrm], red[0]);
  }
}

// ---------------- 4) kv[b,h] = Wk_h (G_b Wv_h^T) + rank-1 terms ----------------
__global__ __launch_bounds__(256) void kv_k(const float* __restrict__ Wk,
                                            const float* __restrict__ bk,
                                            const float* __restrict__ bv,
                                            float* __restrict__ ws) {
  const int bh = blockIdx.x, b = bh >> 3, h = bh & 7;
  const int o0 = blockIdx.y * 1024 + threadIdx.x * 4;
  const int m = o0 >> 6, d0 = o0 & 63;
  const float* pv = ws + o_Pv + (size_t)b * 131072 + h * 64 + d0;
  const float* wk = Wk + (size_t)(h * 64 + m) * 256;
  float acc[4] = {0.f, 0.f, 0.f, 0.f};
  for (int i = 0; i < 256; ++i) {
    const float w = wk[i];
    const float4 p = *(const float4*)&pv[(size_t)i * 512];
    acc[0] += w * p.x; acc[1] += w * p.y; acc[2] += w * p.z; acc[3] += w * p.w;
  }
  const float wkum = ws[o_wku + b * 512 + h * 64 + m];
  const float bkm = bk[h * 64 + m];
  const float* wvup = ws + o_wvu + b * 512 + h * 64 + d0;
  const float* bvp = bv + h * 64 + d0;
  float rr[4];
#pragma unroll
  for (int e = 0; e < 4; ++e)
    rr[e] = acc[e] + wkum * bvp[e] + bkm * wvup[e] + (float)N_ * bkm * bvp[e];
  *(float4*)&ws[o_kv + (size_t)bh * 4096 + (size_t)m * 64 + d0] =
      make_float4(rr[0], rr[1], rr[2], rr[3]);
}

// ---------------- 5) W1bt/w2bt (bf16, K-major) + C1/C2 (fp32), fold s ----------------
// grid (4 b, 256 i), 512 threads
__global__ __launch_bounds__(512) void w1_k(const float* __restrict__ Wq,
                                            const float* __restrict__ bq,
                                            float* __restrict__ ws) {
  const int b = blockIdx.x, i = blockIdx.y;
  const int c = threadIdx.x, h = c >> 6, d = c & 63;
  const float s = 1.f / (sqrtf(ws[o_nrm]) * sqrtf(ws[o_nrm + 1]));
  const float* kvp = ws + o_kv + (size_t)(b * 8 + h) * 4096 + d;
  unsigned short* W1bt = (unsigned short*)(ws + o_W1bt) + (size_t)b * 131072;
  unsigned short* w2bt = (unsigned short*)(ws + o_w2bt) + b * 4096;
  float a = 0.f;
#pragma unroll 4
  for (int m = 0; m < 64; ++m) a += Wq[(size_t)(h * 64 + m) * 256 + i] * kvp[(size_t)m * 64];
  W1bt[(size_t)c * 256 + i] = f2b(s * a);
  if (c < 16) {
    float w = 0.f;
    if (c < 8) {
      const float* ksp = ws + o_kssum + b * 512 + c * 64;
#pragma unroll 4
      for (int m = 0; m < 64; ++m) w += Wq[(size_t)(c * 64 + m) * 256 + i] * ksp[m];
    }
    w2bt[c * 256 + i] = f2b(s * w);
  }
  if (i == 0) {
    float c1 = 0.f;
    for (int m = 0; m < 64; ++m) c1 += bq[h * 64 + m] * kvp[(size_t)m * 64];
    ws[o_C1 + b * 512 + c] = s * c1 + ws[o_vssum + b * 512 + c];
    if (c < 8) {
      float c2 = 0.f;
      const float* ksp = ws + o_kssum + b * 512 + c * 64;
      for (int m = 0; m < 64; ++m) c2 += bq[c * 64 + m] * ksp[m];
      ws[o_C2 + b * 8 + c] = s * c2 + (float)N_;
    }
  }
}

// ---------------- 6) output: num/den via bf16 MFMA + fused epilogue ----------------
// grid (R/64), 256 threads (4 waves). Wave w owns output cols d = w*16..w*16+15 for ALL 8 heads.
__global__ __launch_bounds__(256) void out_k(const float* __restrict__ X,
                                             const float* __restrict__ ws,
                                             float* __restrict__ out) {
  const int r0 = blockIdx.x * 64;
  const int b = blockIdx.x >> 8;   // 16384/64 = 256 blocks per batch
  const int tid = threadIdx.x;
  const int lane = tid & 63, wv = tid >> 6;
  const int lc = lane & 15;
  const int klb = (lane >> 4) * 16;

  __shared__ __align__(16) unsigned short Xs[64 * 256];  // [row][256k] bf16, swizzled
  __shared__ float invden[64][9];
  char* Xb = (char*)Xs;

  // stage X rows (fp32 -> bf16), row-major K-consecutive, XOR swizzle
  {
    const int row = tid >> 2, kq = (tid & 3) * 64;
    const float* src = X + (size_t)(r0 + row) * DIN + kq;
    const int swz = (row & 7) << 4;
#pragma unroll
    for (int g = 0; g < 8; ++g) {
      const float4 v0 = *(const float4*)(src + g * 8);
      const float4 v1 = *(const float4*)(src + g * 8 + 4);
      short8 p;
      p[0] = (short)f2b(v0.x); p[1] = (short)f2b(v0.y);
      p[2] = (short)f2b(v0.z); p[3] = (short)f2b(v0.w);
      p[4] = (short)f2b(v1.x); p[5] = (short)f2b(v1.y);
      p[6] = (short)f2b(v1.z); p[7] = (short)f2b(v1.w);
      *(short8*)(Xb + ((row * 512 + (kq + g * 8) * 2) ^ swz)) = p;
    }
  }
  __syncthreads();

  const char* W1b = (const char*)((const unsigned short*)(ws + o_W1bt) + (size_t)b * 131072);
  const char* w2b = (const char*)((const unsigned short*)(ws + o_w2bt) + b * 4096);

  f32x4 acc[4][8] = {};
  f32x4 acc2[4] = {};
#pragma unroll
  for (int k32 = 0; k32 < 8; ++k32) {
    const int kbyte = k32 * 64;
    short8 a[4];
#pragma unroll
    for (int fi = 0; fi < 4; ++fi) {
      const int row = fi * 16 + lc;
      a[fi] = *(const short8*)(Xb + ((row * 512 + kbyte + klb) ^ ((row & 7) << 4)));
    }
    short8 bb[8];
#pragma unroll
    for (int fj = 0; fj < 8; ++fj) {
      const int cc = fj * 64 + wv * 16 + lc;
      bb[fj] = *(const short8*)(W1b + cc * 512 + kbyte + klb);
    }
    if (wv == 0) {
      const short8 b2 = *(const short8*)(w2b + lc * 512 + kbyte + klb);
#pragma unroll
      for (int fi = 0; fi < 4; ++fi)
        acc2[fi] = __builtin_amdgcn_mfma_f32_16x16x32_bf16(a[fi], b2, acc2[fi], 0, 0, 0);
    }
#pragma unroll
    for (int fi = 0; fi < 4; ++fi)
#pragma unroll
      for (int fj = 0; fj < 8; ++fj)
        acc[fi][fj] = __builtin_amdgcn_mfma_f32_16x16x32_bf16(a[fi], bb[fj], acc[fi][fj], 0, 0, 0);
  }

  // den -> invden in LDS (wave 0; D layout col=lane&15=h, row=(lane>>4)*4+reg)
  if (wv == 0 && lc < 8) {
    const float c2 = ws[o_C2 + b * 8 + lc];
#pragma unroll
    for (int fi = 0; fi < 4; ++fi) {
      const int rb = fi * 16 + (lane >> 4) * 4;
#pragma unroll
      for (int r = 0; r < 4; ++r) invden[rb + r][lc] = 1.f / (acc2[fi][r] + c2);
    }
  }
  __syncthreads();

  const float* C1p = ws + o_C1 + b * 512;
  float cf[8];
#pragma unroll
  for (int fj = 0; fj < 8; ++fj) cf[fj] = C1p[fj * 64 + wv * 16 + lc];

#pragma unroll
  for (int fi = 0; fi < 4; ++fi) {
    const int rb = fi * 16 + (lane >> 4) * 4;
    float o[4] = {0.f, 0.f, 0.f, 0.f};
#pragma unroll
    for (int fj = 0; fj < 8; ++fj)
#pragma unroll
      for (int r = 0; r < 4; ++r)
        o[r] += (acc[fi][fj][r] + cf[fj]) * invden[rb + r][fj];
#pragma unroll
    for (int r = 0; r < 4; ++r)
      out[(size_t)(r0 + rb + r) * 64 + wv * 16 + lc] = o[r] * 0.125f;
  }
}

extern "C" void kernel_launch(void* const* d_in, const int* in_sizes, int n_in,
                              void* d_out, int out_size, void* d_ws, size_t ws_size,
                              hipStream_t stream) {
  const float* Xq = (const float*)d_in[0];
  const float* Xsrc = (const float*)d_in[1];
  const float* Wq = (const float*)d_in[2];
  const float* bq = (const float*)d_in[3];
  const float* Wk = (const float*)d_in[4];
  const float* bk = (const float*)d_in[5];
  const float* Wv = (const float*)d_in[6];
  const float* bv = (const float*)d_in[7];
  float* out = (float*)d_out;
  float* ws = (float*)d_ws;
  if (ws_size < WS_FLOATS * sizeof(float)) return;  // need ~7.7 MB scratch

  hipMemsetAsync(ws, 0, ZERO_FLOATS * sizeof(float), stream);
  gram_k<<<dim3(32, 8), 512, 0, stream>>>(Xq, Xsrc, ws);
  p_k<<<dim3(8, 4, 9), 256, 0, stream>>>(Wq, Wk, Wv, ws);
  s1_k<<<dim3(8, 5), 256, 0, stream>>>(Wq, Wk, Wv, bq, bk, bv, ws);
  kv_k<<<dim3(32, 4), 256, 0, stream>>>(Wk, bk, bv, ws);
  w1_k<<<dim3(4, 256), 512, 0, stream>>>(Wq, bq, ws);
  out_k<<<dim3(1024), 256, 0, stream>>>(Xq, ws, out);
}